// Round 21
// baseline (354.611 us; speedup 1.0000x reference)
//
#include <hip/hip_runtime.h>
#include <hip/hip_bf16.h>
#include <hip/hip_cooperative_groups.h>
#include <cfloat>

namespace cg = cooperative_groups;

#define BB 16
#define NN 512
#define DIMX 78
#define NH 6
#define DHH 13
#define QS 16                      // f16 row stride (ushorts) for q
#define KS 16                      // f16 row stride (ushorts) for k/v
#define NC (NH*3*DHH)              // 234
#define SCALE 0.27735009811261457f // 13^-0.5
#define LAM_A 1.0f
#define LAM_G 0.5f
#define NU 32

typedef unsigned short ushortx;
typedef _Float16 halfx;
typedef halfx half2v __attribute__((ext_vector_type(2)));

__device__ __forceinline__ ushortx f2h(float f) {
  halfx h = (halfx)f;
  return __builtin_bit_cast(unsigned short, h);
}
__device__ __forceinline__ float h2lo(unsigned d) {
  return (float)__builtin_bit_cast(half2v, d).x;
}
__device__ __forceinline__ float h2hi(unsigned d) {
  return (float)__builtin_bit_cast(half2v, d).y;
}
__device__ __forceinline__ float dot2acc(unsigned qd, unsigned kd, float c) {
#if __has_builtin(__builtin_amdgcn_fdot2)
  return __builtin_amdgcn_fdot2(__builtin_bit_cast(half2v, qd),
                                __builtin_bit_cast(half2v, kd), c, false);
#else
  half2v qa = __builtin_bit_cast(half2v, qd);
  half2v ka = __builtin_bit_cast(half2v, kd);
  c = fmaf((float)qa.x, (float)qa.x, c);
  return fmaf((float)qa.y, (float)ka.y, c);
#endif
}

// ================= device phase bodies (shared by fused & fallback) =========

__device__ __forceinline__ void qkv_body(
    int idx, const float* __restrict__ x, const float* __restrict__ Wqkv,
    ushortx* __restrict__ qh, ushortx* __restrict__ kh, ushortx* __restrict__ vh) {
  const int NQ = 59;
  int rq = idx / NQ, cq = idx % NQ;
  if (rq >= (BB * NN) / 4) return;
  int c0 = cq * 4; if (c0 > NC - 4) c0 = NC - 4;
  int r0 = rq * 4;
  const float* x0 = x + (size_t)r0 * DIMX;
  const float* wb = Wqkv + c0;

  float acc[4][4];
#pragma unroll
  for (int r = 0; r < 4; ++r)
#pragma unroll
    for (int c = 0; c < 4; ++c) acc[r][c] = 0.f;

#pragma unroll 2
  for (int d0 = 0; d0 < 76; d0 += 4) {
    float2 wA[4], wB[4];
#pragma unroll
    for (int dd = 0; dd < 4; ++dd) {
      wA[dd] = *(const float2*)(wb + (d0 + dd) * NC);
      wB[dd] = *(const float2*)(wb + (d0 + dd) * NC + 2);
    }
    float2 xv[4][2];
#pragma unroll
    for (int r = 0; r < 4; ++r) {
      xv[r][0] = *(const float2*)(x0 + r * DIMX + d0);
      xv[r][1] = *(const float2*)(x0 + r * DIMX + d0 + 2);
    }
#pragma unroll
    for (int dd = 0; dd < 4; ++dd) {
#pragma unroll
      for (int r = 0; r < 4; ++r) {
        float xvv = (dd < 2) ? ((dd & 1) ? xv[r][0].y : xv[r][0].x)
                             : ((dd & 1) ? xv[r][1].y : xv[r][1].x);
        acc[r][0] = fmaf(xvv, wA[dd].x, acc[r][0]);
        acc[r][1] = fmaf(xvv, wA[dd].y, acc[r][1]);
        acc[r][2] = fmaf(xvv, wB[dd].x, acc[r][2]);
        acc[r][3] = fmaf(xvv, wB[dd].y, acc[r][3]);
      }
    }
  }
#pragma unroll
  for (int dd = 0; dd < 2; ++dd) {
    int d = 76 + dd;
    float2 wA = *(const float2*)(wb + d * NC);
    float2 wB = *(const float2*)(wb + d * NC + 2);
#pragma unroll
    for (int r = 0; r < 4; ++r) {
      float xvv = x0[r * DIMX + d];
      acc[r][0] = fmaf(xvv, wA.x, acc[r][0]);
      acc[r][1] = fmaf(xvv, wA.y, acc[r][1]);
      acc[r][2] = fmaf(xvv, wB.x, acc[r][2]);
      acc[r][3] = fmaf(xvv, wB.y, acc[r][3]);
    }
  }

#pragma unroll
  for (int r = 0; r < 4; ++r) {
    int bn = r0 + r;
    int b = bn / NN, n = bn % NN;
#pragma unroll
    for (int c = 0; c < 4; ++c) {
      int col = c0 + c;
      int h  = col / (3 * DHH);
      int rm = col % (3 * DHH);
      int t  = rm / DHH;
      int dd = rm % DHH;
      size_t rowb = ((size_t)b * NH + h) * NN + n;
      if (t == 0)      qh[rowb * QS + dd] = f2h(acc[r][c] * SCALE);
      else if (t == 1) kh[rowb * KS + dd] = f2h(acc[r][c]);
      else             vh[rowb * KS + dd] = f2h(acc[r][c]);
    }
  }
}

struct AttnS {
  uint4 k0s[NN], k1s[NN], v0s[NN], v1s[NN];
  unsigned qs[64][8];
  short jact[NN];
  unsigned char ract[64];
  float vsum[DHH];
  float vpart[2][DHH];
  int nact, nract;
};
struct ProjS {
  float Ws[DIMX][80];
  float as[32][82];
  float bs[80];
};
union SmemU { AttnS a; ProjS p; };

__device__ void attn_body(
    AttnS* sm, int d0,
    const ushortx* __restrict__ qh, const ushortx* __restrict__ kh,
    const ushortx* __restrict__ vh, const int* __restrict__ mask,
    const float* __restrict__ adj, float* __restrict__ att) {
  int orig  = (d0 & 7) * 96 + (d0 >> 3);  // bijective: 768 = 8 XCDs * 96
  int itile = orig & 7;
  int bh    = orig >> 3;
  int b     = bh / NH;
  int h     = bh % NH;
  int i0    = itile * 64;

  const ushortx* qb  = qh + (size_t)bh * NN * QS;
  const ushortx* kbb = kh + (size_t)bh * NN * KS;
  const ushortx* vbb = vh + (size_t)bh * NN * KS;
  const int* mrow = mask + b * NN;

  int tid  = threadIdx.x;
  int wave = tid >> 6, lane = tid & 63;

  if (wave == 0) {
    unsigned m8 = 0;
#pragma unroll
    for (int t = 0; t < 8; ++t) {
      int j = lane * 8 + t;
      if (mrow[j] != 0) m8 |= (1u << t);
    }
    int cnt = __popc(m8);
    int pre = cnt;
#pragma unroll
    for (int off = 1; off < 64; off <<= 1) {
      int o = __shfl_up(pre, off);
      if (lane >= off) pre += o;
    }
    pre -= cnt;
    int w = pre;
#pragma unroll
    for (int t = 0; t < 8; ++t)
      if ((m8 >> t) & 1) sm->jact[w++] = (short)(lane * 8 + t);
    if (lane == 63) sm->nact = pre + cnt;
  } else if (wave == 1) {
    int a = (mrow[i0 + lane] != 0) ? 1 : 0;
    int pre = a;
#pragma unroll
    for (int off = 1; off < 64; off <<= 1) {
      int o = __shfl_up(pre, off);
      if (lane >= off) pre += o;
    }
    pre -= a;
    if (a) sm->ract[pre] = (unsigned char)lane;
    if (lane == 63) sm->nract = pre + a;
  } else {
    int idx2 = (wave - 2) * 64 + lane;
    float vp[DHH];
#pragma unroll
    for (int d = 0; d < DHH; ++d) vp[d] = 0.f;
#pragma unroll
    for (int rep = 0; rep < 4; ++rep) {
      const ushortx* vr = vbb + (size_t)(idx2 + rep * 128) * KS;
      uint4 f0 = *(const uint4*)(vr);
      uint4 f1 = *(const uint4*)(vr + 8);
      vp[0] += h2lo(f0.x); vp[1] += h2hi(f0.x);
      vp[2] += h2lo(f0.y); vp[3] += h2hi(f0.y);
      vp[4] += h2lo(f0.z); vp[5] += h2hi(f0.z);
      vp[6] += h2lo(f0.w); vp[7] += h2hi(f0.w);
      vp[8] += h2lo(f1.x); vp[9] += h2hi(f1.x);
      vp[10] += h2lo(f1.y); vp[11] += h2hi(f1.y);
      vp[12] += h2lo(f1.z);
    }
#pragma unroll
    for (int off = 1; off < 64; off <<= 1)
#pragma unroll
      for (int d = 0; d < DHH; ++d) vp[d] += __shfl_xor(vp[d], off);
    if (lane < DHH) sm->vpart[wave - 2][lane] = vp[lane];
  }
  __syncthreads();

  int na = sm->nact;
  int nr = sm->nract;

  {
    int r = tid >> 2, c2 = (tid & 3) * 2;
    *(uint2*)&sm->qs[r][c2] = *(const uint2*)(qb + (size_t)(i0 + r) * QS + c2 * 2);
  }
  for (int t = tid; t < NN; t += 256) {
    if (t < na) {
      int j = sm->jact[t];
      const ushortx* kr = kbb + (size_t)j * KS;
      const ushortx* vr = vbb + (size_t)j * KS;
      uint4 ka = *(const uint4*)(kr);
      uint4 kc = *(const uint4*)(kr + 8);
      kc.z &= 0xFFFFu;
      kc.w = 0;
      sm->k0s[t] = ka;
      sm->k1s[t] = kc;
      sm->v0s[t] = *(const uint4*)(vr);
      sm->v1s[t] = *(const uint4*)(vr + 8);
    } else {
      uint4 z = make_uint4(0, 0, 0, 0);
      sm->k0s[t] = z; sm->k1s[t] = z; sm->v0s[t] = z; sm->v1s[t] = z;
      sm->jact[t] = 0;
    }
  }
  if (tid < DHH) sm->vsum[tid] = sm->vpart[0][tid] + sm->vpart[1][tid];
  __syncthreads();

  for (int e = tid; e < 64 * DHH; e += 256) {
    int r = e / DHH, d = e % DHH;
    int i = i0 + r;
    if (mrow[i] == 0)
      att[((size_t)b * NN + i) * DIMX + h * DHH + d] = (LAM_A / 512.f) * sm->vsum[d];
  }

  int grp = lane >> 4;
  int li  = lane & 15;

  for (int base = wave * 4; base < nr; base += 16) {
    int ridx = base + grp;
    bool rok = ridx < nr;
    int rl = sm->ract[rok ? ridx : 0];
    int i  = i0 + rl;
    unsigned qd[7];
#pragma unroll
    for (int p = 0; p < 7; ++p) qd[p] = sm->qs[rl][p];
    const float* adjr = adj + ((size_t)b * NN + i) * NN;

    float s[NU], aj[NU];
    float sum = 0.f;
#pragma unroll
    for (int u = 0; u < NU; ++u) {
      if (u * 16 < na) {
        int t = u * 16 + li;
        uint4 ka = sm->k0s[t];
        uint4 kc = sm->k1s[t];
        aj[u] = adjr[sm->jact[t]];
        float dot = dot2acc(qd[0], ka.x, 0.f);
        dot = dot2acc(qd[1], ka.y, dot);
        dot = dot2acc(qd[2], ka.z, dot);
        dot = dot2acc(qd[3], ka.w, dot);
        dot = dot2acc(qd[4], kc.x, dot);
        dot = dot2acc(qd[5], kc.y, dot);
        dot = dot2acc(qd[6], kc.z, dot);
        float p = __expf((t < na) ? dot : -FLT_MAX);
        s[u] = p;
        sum += p;
      }
    }
#pragma unroll
    for (int off = 1; off < 16; off <<= 1) sum += __shfl_xor(sum, off);
    float inv = LAM_A / sum;

    float acc[DHH];
#pragma unroll
    for (int d = 0; d < DHH; ++d) acc[d] = 0.f;
#pragma unroll
    for (int u = 0; u < NU; ++u) {
      if (u * 16 < na) {
        int t = u * 16 + li;
        uint4 va = sm->v0s[t];
        uint4 vc = sm->v1s[t];
        float wu = fmaf(LAM_G, aj[u], s[u] * inv);
        acc[0]  = fmaf(h2lo(va.x), wu, acc[0]);
        acc[1]  = fmaf(h2hi(va.x), wu, acc[1]);
        acc[2]  = fmaf(h2lo(va.y), wu, acc[2]);
        acc[3]  = fmaf(h2hi(va.y), wu, acc[3]);
        acc[4]  = fmaf(h2lo(va.z), wu, acc[4]);
        acc[5]  = fmaf(h2hi(va.z), wu, acc[5]);
        acc[6]  = fmaf(h2lo(va.w), wu, acc[6]);
        acc[7]  = fmaf(h2hi(va.w), wu, acc[7]);
        acc[8]  = fmaf(h2lo(vc.x), wu, acc[8]);
        acc[9]  = fmaf(h2hi(vc.x), wu, acc[9]);
        acc[10] = fmaf(h2lo(vc.y), wu, acc[10]);
        acc[11] = fmaf(h2hi(vc.y), wu, acc[11]);
        acc[12] = fmaf(h2lo(vc.z), wu, acc[12]);
      }
    }
#pragma unroll
    for (int off = 1; off < 16; off <<= 1) {
#pragma unroll
      for (int d = 0; d < DHH; ++d) acc[d] += __shfl_xor(acc[d], off);
    }

    if (rok && li == 0) {
#pragma unroll
      for (int d = 0; d < DHH; ++d)
        att[((size_t)b * NN + i) * DIMX + h * DHH + d] = acc[d];
    }
  }
}

__device__ void proj_body(
    ProjS* sp, int blk, int nthreads,
    const float* __restrict__ att, const float* __restrict__ Wout,
    const float* __restrict__ bout, float* __restrict__ out) {
  int tid = threadIdx.x;
  for (int e = tid; e < DIMX * 80; e += nthreads) {
    int r = e / 80, c = e % 80;
    sp->Ws[r][c] = (c < DIMX) ? Wout[r * DIMX + c] : 0.f;
  }
  if (tid < 80) sp->bs[tid] = (tid < DIMX) ? bout[tid] : 0.f;
  size_t row0 = (size_t)blk * 32;
  for (int e = tid; e < 32 * DIMX; e += nthreads)
    sp->as[e / DIMX][e % DIMX] = att[row0 * DIMX + e];
  __syncthreads();

  for (int w = tid; w < 320; w += nthreads) {
    int r2 = w / 20, cq = w % 20;
    int c0 = cq * 4;
    float acc0[4], acc1[4];
#pragma unroll
    for (int kk = 0; kk < 4; ++kk) { acc0[kk] = sp->bs[c0 + kk]; acc1[kk] = sp->bs[c0 + kk]; }
#pragma unroll 6
    for (int d = 0; d < DIMX; ++d) {
      float4 wv = *(const float4*)&sp->Ws[d][c0];
      float a0 = sp->as[r2 * 2 + 0][d];
      float a1 = sp->as[r2 * 2 + 1][d];
      acc0[0] = fmaf(a0, wv.x, acc0[0]); acc0[1] = fmaf(a0, wv.y, acc0[1]);
      acc0[2] = fmaf(a0, wv.z, acc0[2]); acc0[3] = fmaf(a0, wv.w, acc0[3]);
      acc1[0] = fmaf(a1, wv.x, acc1[0]); acc1[1] = fmaf(a1, wv.y, acc1[1]);
      acc1[2] = fmaf(a1, wv.z, acc1[2]); acc1[3] = fmaf(a1, wv.w, acc1[3]);
    }
    size_t r0o = (row0 + r2 * 2) * (size_t)DIMX;
    *(float2*)&out[r0o + c0]        = make_float2(acc0[0], acc0[1]);
    *(float2*)&out[r0o + DIMX + c0] = make_float2(acc1[0], acc1[1]);
    if (cq < 19) {
      *(float2*)&out[r0o + c0 + 2]        = make_float2(acc0[2], acc0[3]);
      *(float2*)&out[r0o + DIMX + c0 + 2] = make_float2(acc1[2], acc1[3]);
    }
  }
}

// ================= fused cooperative kernel =================
__global__ __launch_bounds__(256, 3) void fused_kernel(
    const float* __restrict__ x, const float* __restrict__ Wqkv,
    const int* __restrict__ mask, const float* __restrict__ adj,
    const float* __restrict__ Wout, const float* __restrict__ bout,
    ushortx* __restrict__ qh, ushortx* __restrict__ kh, ushortx* __restrict__ vh,
    float* __restrict__ att, float* __restrict__ out) {
  __shared__ SmemU smem;
  cg::grid_group grid = cg::this_grid();

  // phase 1: qkv (blocks 0..471 carry work)
  qkv_body(blockIdx.x * 256 + threadIdx.x, x, Wqkv, qh, kh, vh);
  grid.sync();

  // phase 2: attention (all 768 blocks)
  attn_body(&smem.a, blockIdx.x, qh, kh, vh, mask, adj, att);
  grid.sync();

  // phase 3: projection (blocks 0..255 carry work)
  if (blockIdx.x < 256)
    proj_body(&smem.p, blockIdx.x, 256, att, Wout, bout, out);
}

// ================= fallback standalone kernels (R18 path) =================
__global__ __launch_bounds__(256) void qkv_kernel(
    const float* __restrict__ x, const float* __restrict__ Wqkv,
    ushortx* __restrict__ qh, ushortx* __restrict__ kh, ushortx* __restrict__ vh) {
  qkv_body(blockIdx.x * 256 + threadIdx.x, x, Wqkv, qh, kh, vh);
}

__global__ __launch_bounds__(256, 4) void attn_kernel(
    const ushortx* __restrict__ qh, const ushortx* __restrict__ kh,
    const ushortx* __restrict__ vh, const int* __restrict__ mask,
    const float* __restrict__ adj, float* __restrict__ att) {
  __shared__ AttnS sm;
  attn_body(&sm, blockIdx.x, qh, kh, vh, mask, adj, att);
}

__global__ __launch_bounds__(256) void proj_kernel(
    const float* __restrict__ att, const float* __restrict__ Wout,
    const float* __restrict__ bout, float* __restrict__ out) {
  __shared__ ProjS sp;
  proj_body(&sp, blockIdx.x, 256, att, Wout, bout, out);
}

extern "C" void kernel_launch(void* const* d_in, const int* in_sizes, int n_in,
                              void* d_out, int out_size, void* d_ws, size_t ws_size,
                              hipStream_t stream) {
  const float* x    = (const float*)d_in[0];
  const int*   mask = (const int*)d_in[1];
  const float* adj  = (const float*)d_in[2];
  const float* Wqkv = (const float*)d_in[3];
  const float* Wout = (const float*)d_in[4];
  const float* bout = (const float*)d_in[5];
  float* out = (float*)d_out;

  const size_t heads_rows = (size_t)BB * NH * NN;           // 49152
  float*   att = (float*)d_ws;                              // BB*NN*DIMX f32
  ushortx* qhp = (ushortx*)(att + (size_t)BB * NN * DIMX);  // heads_rows*QS ush
  ushortx* khp = qhp + heads_rows * QS;
  ushortx* vhp = khp + heads_rows * KS;

  void* kargs[] = {(void*)&x, (void*)&Wqkv, (void*)&mask, (void*)&adj,
                   (void*)&Wout, (void*)&bout, (void*)&qhp, (void*)&khp,
                   (void*)&vhp, (void*)&att, (void*)&out};
  hipError_t err = hipLaunchCooperativeKernel(
      (const void*)fused_kernel, dim3(BB * NH * (NN / 64)), dim3(256),
      kargs, 0, stream);
  if (err != hipSuccess) {
    (void)hipGetLastError();  // clear sticky error, fall back to 3-kernel path
    const int NQ = 59;
    int qkv_threads = (BB * NN / 4) * NQ;
    qkv_kernel<<<(qkv_threads + 255) / 256, 256, 0, stream>>>(x, Wqkv, qhp, khp, vhp);
    attn_kernel<<<BB * NH * (NN / 64), 256, 0, stream>>>(qhp, khp, vhp, mask, adj, att);
    proj_kernel<<<BB * NN / 32, 256, 0, stream>>>(att, Wout, bout, out);
  }
}

// Round 22
// 52.963 us; speedup vs baseline: 6.6955x; 6.6955x over previous
//
#include <hip/hip_runtime.h>
#include <hip/hip_bf16.h>
#include <cfloat>

#define BB 16
#define NN 512
#define DIMX 78
#define NH 6
#define DHH 13
#define QS 16                      // f16 row stride (ushorts) for q
#define KS 16                      // f16 row stride (ushorts) for k/v
#define NC (NH*3*DHH)              // 234
#define SCALE 0.27735009811261457f // 13^-0.5
#define LAM_A 1.0f
#define LAM_G 0.5f
#define NU 32

typedef unsigned short ushortx;
typedef ushortx ushort8 __attribute__((ext_vector_type(8)));
typedef _Float16 halfx;
typedef halfx half2v __attribute__((ext_vector_type(2)));

__device__ __forceinline__ ushortx f2h(float f) {
  halfx h = (halfx)f;
  return __builtin_bit_cast(unsigned short, h);
}
__device__ __forceinline__ float h2lo(unsigned d) {
  return (float)__builtin_bit_cast(half2v, d).x;
}
__device__ __forceinline__ float h2hi(unsigned d) {
  return (float)__builtin_bit_cast(half2v, d).y;
}

// packed f16 dot-2 with f32 accumulate (v_dot2_f32_f16); safe fallback
__device__ __forceinline__ float dot2acc(unsigned qd, unsigned kd, float c) {
#if __has_builtin(__builtin_amdgcn_fdot2)
  return __builtin_amdgcn_fdot2(__builtin_bit_cast(half2v, qd),
                                __builtin_bit_cast(half2v, kd), c, false);
#else
  half2v qa = __builtin_bit_cast(half2v, qd);
  half2v ka = __builtin_bit_cast(half2v, kd);
  c = fmaf((float)qa.x, (float)ka.x, c);
  return fmaf((float)qa.y, (float)ka.y, c);
#endif
}

// ---------------- QKV projection: (B*N, 78) @ (78, 234) ----------------
// thread = 4 rows x 4 cols register tile; d chunked by 4 with float2 loads.
// q written PRE-SCALED as f16; k,v as f16 (fdot2 / fma_mix operands).
__global__ __launch_bounds__(256) void qkv_kernel(
    const float* __restrict__ x, const float* __restrict__ Wqkv,
    ushortx* __restrict__ qh, ushortx* __restrict__ kh, ushortx* __restrict__ vh) {
  int idx = blockIdx.x * 256 + threadIdx.x;
  const int NQ = 59;
  int rq = idx / NQ, cq = idx % NQ;
  if (rq >= (BB * NN) / 4) return;
  int c0 = cq * 4; if (c0 > NC - 4) c0 = NC - 4;  // c0 even -> float2 ok
  int r0 = rq * 4;
  const float* x0 = x + (size_t)r0 * DIMX;
  const float* wb = Wqkv + c0;

  float acc[4][4];
#pragma unroll
  for (int r = 0; r < 4; ++r)
#pragma unroll
    for (int c = 0; c < 4; ++c) acc[r][c] = 0.f;

#pragma unroll 2
  for (int d0 = 0; d0 < 76; d0 += 4) {
    float2 wA[4], wB[4];
#pragma unroll
    for (int dd = 0; dd < 4; ++dd) {
      wA[dd] = *(const float2*)(wb + (d0 + dd) * NC);
      wB[dd] = *(const float2*)(wb + (d0 + dd) * NC + 2);
    }
    float2 xv[4][2];
#pragma unroll
    for (int r = 0; r < 4; ++r) {
      xv[r][0] = *(const float2*)(x0 + r * DIMX + d0);
      xv[r][1] = *(const float2*)(x0 + r * DIMX + d0 + 2);
    }
#pragma unroll
    for (int dd = 0; dd < 4; ++dd) {
#pragma unroll
      for (int r = 0; r < 4; ++r) {
        float xvv = (dd < 2) ? ((dd & 1) ? xv[r][0].y : xv[r][0].x)
                             : ((dd & 1) ? xv[r][1].y : xv[r][1].x);
        acc[r][0] = fmaf(xvv, wA[dd].x, acc[r][0]);
        acc[r][1] = fmaf(xvv, wA[dd].y, acc[r][1]);
        acc[r][2] = fmaf(xvv, wB[dd].x, acc[r][2]);
        acc[r][3] = fmaf(xvv, wB[dd].y, acc[r][3]);
      }
    }
  }
  // tail d = 76, 77
#pragma unroll
  for (int dd = 0; dd < 2; ++dd) {
    int d = 76 + dd;
    float2 wA = *(const float2*)(wb + d * NC);
    float2 wB = *(const float2*)(wb + d * NC + 2);
#pragma unroll
    for (int r = 0; r < 4; ++r) {
      float xvv = x0[r * DIMX + d];
      acc[r][0] = fmaf(xvv, wA.x, acc[r][0]);
      acc[r][1] = fmaf(xvv, wA.y, acc[r][1]);
      acc[r][2] = fmaf(xvv, wB.x, acc[r][2]);
      acc[r][3] = fmaf(xvv, wB.y, acc[r][3]);
    }
  }

#pragma unroll
  for (int r = 0; r < 4; ++r) {
    int bn = r0 + r;
    int b = bn / NN, n = bn % NN;
#pragma unroll
    for (int c = 0; c < 4; ++c) {
      int col = c0 + c;
      int h  = col / (3 * DHH);
      int rm = col % (3 * DHH);
      int t  = rm / DHH;
      int dd = rm % DHH;
      size_t rowb = ((size_t)b * NH + h) * NN + n;
      if (t == 0)      qh[rowb * QS + dd] = f2h(acc[r][c] * SCALE);
      else if (t == 1) kh[rowb * KS + dd] = f2h(acc[r][c]);
      else             vh[rowb * KS + dd] = f2h(acc[r][c]);
    }
  }
}

// ---------------- Fused masked softmax attention ----------------
// grid = 768 blocks; block = 256 (4 waves), 4 blocks/CU. Proven R18 core:
// compacted K/V in LDS (f16), fdot2 QK, fma_mix PV, no max-subtraction,
// XCD swizzle, adj gathers issued in the dot loop (latency hidden).
__global__ __launch_bounds__(256, 4) void attn_kernel(
    const ushortx* __restrict__ qh, const ushortx* __restrict__ kh,
    const ushortx* __restrict__ vh, const int* __restrict__ mask,
    const float* __restrict__ adj, float* __restrict__ att) {
  __shared__ uint4 k0s[NN], k1s[NN];      // f16 elems 0-7, 8-15 (13,14,15 zeroed)
  __shared__ uint4 v0s[NN], v1s[NN];      // f16 elems 0-7, 8-15 (pads unread)
  __shared__ __align__(16) unsigned qs[64][8];  // f16 pairs, 32B/row
  __shared__ short jact[NN];
  __shared__ unsigned char ract[64];
  __shared__ float vsum[DHH];
  __shared__ float vpart_s[2][DHH];
  __shared__ int nact_s, nract_s;

  int d0    = blockIdx.x;
  int orig  = (d0 & 7) * 96 + (d0 >> 3);  // bijective: 768 = 8 XCDs * 96
  int itile = orig & 7;
  int bh    = orig >> 3;                  // b-major: bh = b*NH + h
  int b     = bh / NH;
  int h     = bh % NH;
  int i0    = itile * 64;

  const ushortx* qb  = qh + (size_t)bh * NN * QS;
  const ushortx* kbb = kh + (size_t)bh * NN * KS;
  const ushortx* vbb = vh + (size_t)bh * NN * KS;
  const int* mrow = mask + b * NN;

  int tid  = threadIdx.x;
  int wave = tid >> 6, lane = tid & 63;

  if (wave == 0) {
    // column compaction: lane owns 8 j's, prefix scan over lanes
    unsigned m8 = 0;
#pragma unroll
    for (int t = 0; t < 8; ++t) {
      int j = lane * 8 + t;
      if (mrow[j] != 0) m8 |= (1u << t);
    }
    int cnt = __popc(m8);
    int pre = cnt;
#pragma unroll
    for (int off = 1; off < 64; off <<= 1) {
      int o = __shfl_up(pre, off);
      if (lane >= off) pre += o;
    }
    pre -= cnt;
    int w = pre;
#pragma unroll
    for (int t = 0; t < 8; ++t)
      if ((m8 >> t) & 1) jact[w++] = (short)(lane * 8 + t);
    if (lane == 63) nact_s = pre + cnt;
  } else if (wave == 1) {
    // row compaction for this 64-row tile
    int a = (mrow[i0 + lane] != 0) ? 1 : 0;
    int pre = a;
#pragma unroll
    for (int off = 1; off < 64; off <<= 1) {
      int o = __shfl_up(pre, off);
      if (lane >= off) pre += o;
    }
    pre -= a;
    if (a) ract[pre] = (unsigned char)lane;
    if (lane == 63) nract_s = pre + a;
  } else {
    // waves 2,3: vsum partials over ALL 512 v rows (f16 src, f32 accum)
    int idx2 = (wave - 2) * 64 + lane;  // 0..127
    float vp[DHH];
#pragma unroll
    for (int d = 0; d < DHH; ++d) vp[d] = 0.f;
#pragma unroll
    for (int rep = 0; rep < 4; ++rep) {
      const ushortx* vr = vbb + (size_t)(idx2 + rep * 128) * KS;
      uint4 f0 = *(const uint4*)(vr);
      uint4 f1 = *(const uint4*)(vr + 8);
      vp[0] += h2lo(f0.x); vp[1] += h2hi(f0.x);
      vp[2] += h2lo(f0.y); vp[3] += h2hi(f0.y);
      vp[4] += h2lo(f0.z); vp[5] += h2hi(f0.z);
      vp[6] += h2lo(f0.w); vp[7] += h2hi(f0.w);
      vp[8] += h2lo(f1.x); vp[9] += h2hi(f1.x);
      vp[10] += h2lo(f1.y); vp[11] += h2hi(f1.y);
      vp[12] += h2lo(f1.z);
    }
#pragma unroll
    for (int off = 1; off < 64; off <<= 1)
#pragma unroll
      for (int d = 0; d < DHH; ++d) vp[d] += __shfl_xor(vp[d], off);
    if (lane < DHH) vpart_s[wave - 2][lane] = vp[lane];
  }
  __syncthreads();

  int na = nact_s;
  int nr = nract_s;

  // stage q tile: thread -> 8B chunk, coalesced (f16 rows, 32B each)
  {
    int r = tid >> 2, c2 = (tid & 3) * 2;
    *(uint2*)&qs[r][c2] = *(const uint2*)(qb + (size_t)(i0 + r) * QS + c2 * 2);
  }
  // stage compacted K (f16, zero pad elems 13-15) and V (f16); zero tails
  for (int t = tid; t < NN; t += 256) {
    if (t < na) {
      int j = jact[t];
      const ushortx* kr = kbb + (size_t)j * KS;
      const ushortx* vr = vbb + (size_t)j * KS;
      uint4 ka = *(const uint4*)(kr);
      uint4 kc = *(const uint4*)(kr + 8);
      kc.z &= 0xFFFFu;  // keep elem12, zero elem13
      kc.w = 0;         // zero elems 14,15
      k0s[t] = ka;
      k1s[t] = kc;
      v0s[t] = *(const uint4*)(vr);
      v1s[t] = *(const uint4*)(vr + 8);
    } else {
      uint4 z = make_uint4(0, 0, 0, 0);
      k0s[t] = z; k1s[t] = z; v0s[t] = z; v1s[t] = z;
      jact[t] = 0;
    }
  }
  if (tid < DHH) vsum[tid] = vpart_s[0][tid] + vpart_s[1][tid];
  __syncthreads();

  // fully-masked rows: uniform softmax over all 512, zero adjacency
  for (int e = tid; e < 64 * DHH; e += 256) {
    int r = e / DHH, d = e % DHH;
    int i = i0 + r;
    if (mrow[i] == 0)
      att[((size_t)b * NN + i) * DIMX + h * DHH + d] = (LAM_A / 512.f) * vsum[d];
  }

  int grp = lane >> 4;
  int li  = lane & 15;

  for (int base = wave * 4; base < nr; base += 16) {
    int ridx = base + grp;
    bool rok = ridx < nr;
    int rl = ract[rok ? ridx : 0];
    int i  = i0 + rl;
    // q row as 7 f16-pair dwords (LDS broadcast; elem13 pad unused: k13=0)
    unsigned qd[7];
#pragma unroll
    for (int p = 0; p < 7; ++p) qd[p] = qs[rl][p];
    const float* adjr = adj + ((size_t)b * NN + i) * NN;

    float s[NU], aj[NU];
    float sum = 0.f;
#pragma unroll
    for (int u = 0; u < NU; ++u) {
      if (u * 16 < na) {  // wave-uniform branch
        int t = u * 16 + li;
        uint4 ka = k0s[t];
        uint4 kc = k1s[t];
        aj[u] = adjr[jact[t]];  // prefetched, consumed after softmax
        float dot = dot2acc(qd[0], ka.x, 0.f);
        dot = dot2acc(qd[1], ka.y, dot);
        dot = dot2acc(qd[2], ka.z, dot);
        dot = dot2acc(qd[3], ka.w, dot);
        dot = dot2acc(qd[4], kc.x, dot);
        dot = dot2acc(qd[5], kc.y, dot);
        dot = dot2acc(qd[6], kc.z, dot);  // elems 12,13 (13 zeroed in k)
        // no max-subtraction: |dot| ~ O(1); tail -> exp(-FLT_MAX) = 0
        float p = __expf((t < na) ? dot : -FLT_MAX);
        s[u] = p;
        sum += p;
      }
    }
#pragma unroll
    for (int off = 1; off < 16; off <<= 1) sum += __shfl_xor(sum, off);
    float inv = LAM_A / sum;

    float acc[DHH];
#pragma unroll
    for (int d = 0; d < DHH; ++d) acc[d] = 0.f;
#pragma unroll
    for (int u = 0; u < NU; ++u) {
      if (u * 16 < na) {
        int t = u * 16 + li;
        uint4 va = v0s[t];
        uint4 vc = v1s[t];
        float wu = fmaf(LAM_G, aj[u], s[u] * inv);  // tail rows: v==0 -> 0
        // fpext(f16)*f32+f32 -> v_fma_mix_f32 (13 ops, no extraction)
        acc[0]  = fmaf(h2lo(va.x), wu, acc[0]);
        acc[1]  = fmaf(h2hi(va.x), wu, acc[1]);
        acc[2]  = fmaf(h2lo(va.y), wu, acc[2]);
        acc[3]  = fmaf(h2hi(va.y), wu, acc[3]);
        acc[4]  = fmaf(h2lo(va.z), wu, acc[4]);
        acc[5]  = fmaf(h2hi(va.z), wu, acc[5]);
        acc[6]  = fmaf(h2lo(va.w), wu, acc[6]);
        acc[7]  = fmaf(h2hi(va.w), wu, acc[7]);
        acc[8]  = fmaf(h2lo(vc.x), wu, acc[8]);
        acc[9]  = fmaf(h2hi(vc.x), wu, acc[9]);
        acc[10] = fmaf(h2lo(vc.y), wu, acc[10]);
        acc[11] = fmaf(h2hi(vc.y), wu, acc[11]);
        acc[12] = fmaf(h2lo(vc.z), wu, acc[12]);
      }
    }
#pragma unroll
    for (int off = 1; off < 16; off <<= 1) {
#pragma unroll
      for (int d = 0; d < DHH; ++d) acc[d] += __shfl_xor(acc[d], off);
    }

    if (rok && li == 0) {
#pragma unroll
      for (int d = 0; d < DHH; ++d)
        att[((size_t)b * NN + i) * DIMX + h * DHH + d] = acc[d];
    }
  }
}

// ---------------- Output projection: (B*N,78) @ (78,78) + b ----------------
// block = 320 threads (5 waves), 32 rows/block, thread = 2 rows x 4 cols.
__global__ __launch_bounds__(320) void proj_kernel(
    const float* __restrict__ att, const float* __restrict__ Wout,
    const float* __restrict__ bout, float* __restrict__ out) {
  __shared__ float Ws[DIMX][80];   // padded cols
  __shared__ float as[32][82];     // stride 82: conflict-free row reads
  __shared__ float bs[80];
  int tid = threadIdx.x;
  for (int e = tid; e < DIMX * 80; e += 320) {
    int r = e / 80, c = e % 80;
    Ws[r][c] = (c < DIMX) ? Wout[r * DIMX + c] : 0.f;
  }
  if (tid < 80) bs[tid] = (tid < DIMX) ? bout[tid] : 0.f;
  size_t row0 = (size_t)blockIdx.x * 32;
  for (int e = tid; e < 32 * DIMX; e += 320)
    as[e / DIMX][e % DIMX] = att[row0 * DIMX + e];
  __syncthreads();

  int r2 = tid / 20;   // 0..15 -> rows r2*2, r2*2+1
  int cq = tid % 20;   // 0..19 -> cols cq*4..cq*4+3 (last quad: 2 pad)
  int c0 = cq * 4;
  float acc0[4], acc1[4];
#pragma unroll
  for (int kk = 0; kk < 4; ++kk) { acc0[kk] = bs[c0 + kk]; acc1[kk] = bs[c0 + kk]; }

#pragma unroll 6
  for (int d = 0; d < DIMX; ++d) {
    float4 w = *(const float4*)&Ws[d][c0];
    float a0 = as[r2 * 2 + 0][d];
    float a1 = as[r2 * 2 + 1][d];
    acc0[0] = fmaf(a0, w.x, acc0[0]); acc0[1] = fmaf(a0, w.y, acc0[1]);
    acc0[2] = fmaf(a0, w.z, acc0[2]); acc0[3] = fmaf(a0, w.w, acc0[3]);
    acc1[0] = fmaf(a1, w.x, acc1[0]); acc1[1] = fmaf(a1, w.y, acc1[1]);
    acc1[2] = fmaf(a1, w.z, acc1[2]); acc1[3] = fmaf(a1, w.w, acc1[3]);
  }

  size_t r0o = (row0 + r2 * 2) * (size_t)DIMX;
  *(float2*)&out[r0o + c0]        = make_float2(acc0[0], acc0[1]);
  *(float2*)&out[r0o + DIMX + c0] = make_float2(acc1[0], acc1[1]);
  if (cq < 19) {
    *(float2*)&out[r0o + c0 + 2]        = make_float2(acc0[2], acc0[3]);
    *(float2*)&out[r0o + DIMX + c0 + 2] = make_float2(acc1[2], acc1[3]);
  }
}

extern "C" void kernel_launch(void* const* d_in, const int* in_sizes, int n_in,
                              void* d_out, int out_size, void* d_ws, size_t ws_size,
                              hipStream_t stream) {
  const float* x    = (const float*)d_in[0];
  const int*   mask = (const int*)d_in[1];
  const float* adj  = (const float*)d_in[2];
  const float* Wqkv = (const float*)d_in[3];
  const float* Wout = (const float*)d_in[4];
  const float* bout = (const float*)d_in[5];
  float* out = (float*)d_out;

  const size_t heads_rows = (size_t)BB * NH * NN;           // 49152
  float*   att = (float*)d_ws;                              // BB*NN*DIMX f32
  ushortx* qhp = (ushortx*)(att + (size_t)BB * NN * DIMX);  // heads_rows*QS ush
  ushortx* khp = qhp + heads_rows * QS;
  ushortx* vhp = khp + heads_rows * KS;

  const int NQ = 59;
  int qkv_threads = (BB * NN / 4) * NQ;
  qkv_kernel<<<(qkv_threads + 255) / 256, 256, 0, stream>>>(x, Wqkv, qhp, khp, vhp);
  attn_kernel<<<BB * NH * (NN / 64), 256, 0, stream>>>(qhp, khp, vhp, mask, adj, att);
  proj_kernel<<<BB * NN / 32, 320, 0, stream>>>(att, Wout, bout, out);
}

// Round 23
// 52.610 us; speedup vs baseline: 6.7404x; 1.0067x over previous
//
#include <hip/hip_runtime.h>
#include <hip/hip_bf16.h>
#include <cfloat>

#define BB 16
#define NN 512
#define DIMX 78
#define NH 6
#define DHH 13
#define QS 16                      // f16 row stride (ushorts) for q
#define KS 16                      // f16 row stride (ushorts) for k/v
#define NC (NH*3*DHH)              // 234
#define SCALE 0.27735009811261457f // 13^-0.5
#define LAM_A 1.0f
#define LAM_G 0.5f
#define NU 32

typedef unsigned short ushortx;
typedef ushortx ushort8 __attribute__((ext_vector_type(8)));
typedef _Float16 halfx;
typedef halfx half2v __attribute__((ext_vector_type(2)));

__device__ __forceinline__ ushortx f2h(float f) {
  halfx h = (halfx)f;
  return __builtin_bit_cast(unsigned short, h);
}
__device__ __forceinline__ float h2lo(unsigned d) {
  return (float)__builtin_bit_cast(half2v, d).x;
}
__device__ __forceinline__ float h2hi(unsigned d) {
  return (float)__builtin_bit_cast(half2v, d).y;
}

// packed f16 dot-2 with f32 accumulate (v_dot2_f32_f16); safe fallback
__device__ __forceinline__ float dot2acc(unsigned qd, unsigned kd, float c) {
#if __has_builtin(__builtin_amdgcn_fdot2)
  return __builtin_amdgcn_fdot2(__builtin_bit_cast(half2v, qd),
                                __builtin_bit_cast(half2v, kd), c, false);
#else
  half2v qa = __builtin_bit_cast(half2v, qd);
  half2v ka = __builtin_bit_cast(half2v, kd);
  c = fmaf((float)qa.x, (float)ka.x, c);
  return fmaf((float)qa.y, (float)ka.y, c);
#endif
}

// ---------------- QKV projection: (B*N, 78) @ (78, 234) ----------------
// thread = 4 rows x 4 cols register tile; d chunked by 4 with float2 loads.
// q written PRE-SCALED as f16; k,v as f16 (fdot2 / fma_mix operands).
__global__ __launch_bounds__(256) void qkv_kernel(
    const float* __restrict__ x, const float* __restrict__ Wqkv,
    ushortx* __restrict__ qh, ushortx* __restrict__ kh, ushortx* __restrict__ vh) {
  int idx = blockIdx.x * 256 + threadIdx.x;
  const int NQ = 59;
  int rq = idx / NQ, cq = idx % NQ;
  if (rq >= (BB * NN) / 4) return;
  int c0 = cq * 4; if (c0 > NC - 4) c0 = NC - 4;  // c0 even -> float2 ok
  int r0 = rq * 4;
  const float* x0 = x + (size_t)r0 * DIMX;
  const float* wb = Wqkv + c0;

  float acc[4][4];
#pragma unroll
  for (int r = 0; r < 4; ++r)
#pragma unroll
    for (int c = 0; c < 4; ++c) acc[r][c] = 0.f;

#pragma unroll 2
  for (int d0 = 0; d0 < 76; d0 += 4) {
    float2 wA[4], wB[4];
#pragma unroll
    for (int dd = 0; dd < 4; ++dd) {
      wA[dd] = *(const float2*)(wb + (d0 + dd) * NC);
      wB[dd] = *(const float2*)(wb + (d0 + dd) * NC + 2);
    }
    float2 xv[4][2];
#pragma unroll
    for (int r = 0; r < 4; ++r) {
      xv[r][0] = *(const float2*)(x0 + r * DIMX + d0);
      xv[r][1] = *(const float2*)(x0 + r * DIMX + d0 + 2);
    }
#pragma unroll
    for (int dd = 0; dd < 4; ++dd) {
#pragma unroll
      for (int r = 0; r < 4; ++r) {
        float xvv = (dd < 2) ? ((dd & 1) ? xv[r][0].y : xv[r][0].x)
                             : ((dd & 1) ? xv[r][1].y : xv[r][1].x);
        acc[r][0] = fmaf(xvv, wA[dd].x, acc[r][0]);
        acc[r][1] = fmaf(xvv, wA[dd].y, acc[r][1]);
        acc[r][2] = fmaf(xvv, wB[dd].x, acc[r][2]);
        acc[r][3] = fmaf(xvv, wB[dd].y, acc[r][3]);
      }
    }
  }
  // tail d = 76, 77
#pragma unroll
  for (int dd = 0; dd < 2; ++dd) {
    int d = 76 + dd;
    float2 wA = *(const float2*)(wb + d * NC);
    float2 wB = *(const float2*)(wb + d * NC + 2);
#pragma unroll
    for (int r = 0; r < 4; ++r) {
      float xvv = x0[r * DIMX + d];
      acc[r][0] = fmaf(xvv, wA.x, acc[r][0]);
      acc[r][1] = fmaf(xvv, wA.y, acc[r][1]);
      acc[r][2] = fmaf(xvv, wB.x, acc[r][2]);
      acc[r][3] = fmaf(xvv, wB.y, acc[r][3]);
    }
  }

#pragma unroll
  for (int r = 0; r < 4; ++r) {
    int bn = r0 + r;
    int b = bn / NN, n = bn % NN;
#pragma unroll
    for (int c = 0; c < 4; ++c) {
      int col = c0 + c;
      int h  = col / (3 * DHH);
      int rm = col % (3 * DHH);
      int t  = rm / DHH;
      int dd = rm % DHH;
      size_t rowb = ((size_t)b * NH + h) * NN + n;
      if (t == 0)      qh[rowb * QS + dd] = f2h(acc[r][c] * SCALE);
      else if (t == 1) kh[rowb * KS + dd] = f2h(acc[r][c]);
      else             vh[rowb * KS + dd] = f2h(acc[r][c]);
    }
  }
}

// ---------------- Fused masked softmax attention ----------------
// grid = 768 blocks; block = 256 (4 waves), 4 blocks/CU. Proven R18/R22 core
// + s_setprio(1) around each row-iteration's compute (waves are independent
// in this loop -> the m191-favorable case; no register/control-flow impact).
__global__ __launch_bounds__(256, 4) void attn_kernel(
    const ushortx* __restrict__ qh, const ushortx* __restrict__ kh,
    const ushortx* __restrict__ vh, const int* __restrict__ mask,
    const float* __restrict__ adj, float* __restrict__ att) {
  __shared__ uint4 k0s[NN], k1s[NN];      // f16 elems 0-7, 8-15 (13,14,15 zeroed)
  __shared__ uint4 v0s[NN], v1s[NN];      // f16 elems 0-7, 8-15 (pads unread)
  __shared__ __align__(16) unsigned qs[64][8];  // f16 pairs, 32B/row
  __shared__ short jact[NN];
  __shared__ unsigned char ract[64];
  __shared__ float vsum[DHH];
  __shared__ float vpart_s[2][DHH];
  __shared__ int nact_s, nract_s;

  int d0    = blockIdx.x;
  int orig  = (d0 & 7) * 96 + (d0 >> 3);  // bijective: 768 = 8 XCDs * 96
  int itile = orig & 7;
  int bh    = orig >> 3;                  // b-major: bh = b*NH + h
  int b     = bh / NH;
  int h     = bh % NH;
  int i0    = itile * 64;

  const ushortx* qb  = qh + (size_t)bh * NN * QS;
  const ushortx* kbb = kh + (size_t)bh * NN * KS;
  const ushortx* vbb = vh + (size_t)bh * NN * KS;
  const int* mrow = mask + b * NN;

  int tid  = threadIdx.x;
  int wave = tid >> 6, lane = tid & 63;

  if (wave == 0) {
    // column compaction: lane owns 8 j's, prefix scan over lanes
    unsigned m8 = 0;
#pragma unroll
    for (int t = 0; t < 8; ++t) {
      int j = lane * 8 + t;
      if (mrow[j] != 0) m8 |= (1u << t);
    }
    int cnt = __popc(m8);
    int pre = cnt;
#pragma unroll
    for (int off = 1; off < 64; off <<= 1) {
      int o = __shfl_up(pre, off);
      if (lane >= off) pre += o;
    }
    pre -= cnt;
    int w = pre;
#pragma unroll
    for (int t = 0; t < 8; ++t)
      if ((m8 >> t) & 1) jact[w++] = (short)(lane * 8 + t);
    if (lane == 63) nact_s = pre + cnt;
  } else if (wave == 1) {
    // row compaction for this 64-row tile
    int a = (mrow[i0 + lane] != 0) ? 1 : 0;
    int pre = a;
#pragma unroll
    for (int off = 1; off < 64; off <<= 1) {
      int o = __shfl_up(pre, off);
      if (lane >= off) pre += o;
    }
    pre -= a;
    if (a) ract[pre] = (unsigned char)lane;
    if (lane == 63) nract_s = pre + a;
  } else {
    // waves 2,3: vsum partials over ALL 512 v rows (f16 src, f32 accum)
    int idx2 = (wave - 2) * 64 + lane;  // 0..127
    float vp[DHH];
#pragma unroll
    for (int d = 0; d < DHH; ++d) vp[d] = 0.f;
#pragma unroll
    for (int rep = 0; rep < 4; ++rep) {
      const ushortx* vr = vbb + (size_t)(idx2 + rep * 128) * KS;
      uint4 f0 = *(const uint4*)(vr);
      uint4 f1 = *(const uint4*)(vr + 8);
      vp[0] += h2lo(f0.x); vp[1] += h2hi(f0.x);
      vp[2] += h2lo(f0.y); vp[3] += h2hi(f0.y);
      vp[4] += h2lo(f0.z); vp[5] += h2hi(f0.z);
      vp[6] += h2lo(f0.w); vp[7] += h2hi(f0.w);
      vp[8] += h2lo(f1.x); vp[9] += h2hi(f1.x);
      vp[10] += h2lo(f1.y); vp[11] += h2hi(f1.y);
      vp[12] += h2lo(f1.z);
    }
#pragma unroll
    for (int off = 1; off < 64; off <<= 1)
#pragma unroll
      for (int d = 0; d < DHH; ++d) vp[d] += __shfl_xor(vp[d], off);
    if (lane < DHH) vpart_s[wave - 2][lane] = vp[lane];
  }
  __syncthreads();

  int na = nact_s;
  int nr = nract_s;

  // stage q tile: thread -> 8B chunk, coalesced (f16 rows, 32B each)
  {
    int r = tid >> 2, c2 = (tid & 3) * 2;
    *(uint2*)&qs[r][c2] = *(const uint2*)(qb + (size_t)(i0 + r) * QS + c2 * 2);
  }
  // stage compacted K (f16, zero pad elems 13-15) and V (f16); zero tails
  for (int t = tid; t < NN; t += 256) {
    if (t < na) {
      int j = jact[t];
      const ushortx* kr = kbb + (size_t)j * KS;
      const ushortx* vr = vbb + (size_t)j * KS;
      uint4 ka = *(const uint4*)(kr);
      uint4 kc = *(const uint4*)(kr + 8);
      kc.z &= 0xFFFFu;  // keep elem12, zero elem13
      kc.w = 0;         // zero elems 14,15
      k0s[t] = ka;
      k1s[t] = kc;
      v0s[t] = *(const uint4*)(vr);
      v1s[t] = *(const uint4*)(vr + 8);
    } else {
      uint4 z = make_uint4(0, 0, 0, 0);
      k0s[t] = z; k1s[t] = z; v0s[t] = z; v1s[t] = z;
      jact[t] = 0;
    }
  }
  if (tid < DHH) vsum[tid] = vpart_s[0][tid] + vpart_s[1][tid];
  __syncthreads();

  // fully-masked rows: uniform softmax over all 512, zero adjacency
  for (int e = tid; e < 64 * DHH; e += 256) {
    int r = e / DHH, d = e % DHH;
    int i = i0 + r;
    if (mrow[i] == 0)
      att[((size_t)b * NN + i) * DIMX + h * DHH + d] = (LAM_A / 512.f) * vsum[d];
  }

  int grp = lane >> 4;
  int li  = lane & 15;

  for (int base = wave * 4; base < nr; base += 16) {
    int ridx = base + grp;
    bool rok = ridx < nr;
    int rl = ract[rok ? ridx : 0];
    int i  = i0 + rl;
    // q row as 7 f16-pair dwords (LDS broadcast; elem13 pad unused: k13=0)
    unsigned qd[7];
#pragma unroll
    for (int p = 0; p < 7; ++p) qd[p] = qs[rl][p];
    const float* adjr = adj + ((size_t)b * NN + i) * NN;

    __builtin_amdgcn_s_setprio(1);  // favor this wave's compute chain

    float s[NU], aj[NU];
    float sum = 0.f;
#pragma unroll
    for (int u = 0; u < NU; ++u) {
      if (u * 16 < na) {  // wave-uniform branch
        int t = u * 16 + li;
        uint4 ka = k0s[t];
        uint4 kc = k1s[t];
        aj[u] = adjr[jact[t]];  // prefetched, consumed after softmax
        float dot = dot2acc(qd[0], ka.x, 0.f);
        dot = dot2acc(qd[1], ka.y, dot);
        dot = dot2acc(qd[2], ka.z, dot);
        dot = dot2acc(qd[3], ka.w, dot);
        dot = dot2acc(qd[4], kc.x, dot);
        dot = dot2acc(qd[5], kc.y, dot);
        dot = dot2acc(qd[6], kc.z, dot);  // elems 12,13 (13 zeroed in k)
        // no max-subtraction: |dot| ~ O(1); tail -> exp(-FLT_MAX) = 0
        float p = __expf((t < na) ? dot : -FLT_MAX);
        s[u] = p;
        sum += p;
      }
    }
#pragma unroll
    for (int off = 1; off < 16; off <<= 1) sum += __shfl_xor(sum, off);
    float inv = LAM_A / sum;

    float acc[DHH];
#pragma unroll
    for (int d = 0; d < DHH; ++d) acc[d] = 0.f;
#pragma unroll
    for (int u = 0; u < NU; ++u) {
      if (u * 16 < na) {
        int t = u * 16 + li;
        uint4 va = v0s[t];
        uint4 vc = v1s[t];
        float wu = fmaf(LAM_G, aj[u], s[u] * inv);  // tail rows: v==0 -> 0
        // fpext(f16)*f32+f32 -> v_fma_mix_f32 (13 ops, no extraction)
        acc[0]  = fmaf(h2lo(va.x), wu, acc[0]);
        acc[1]  = fmaf(h2hi(va.x), wu, acc[1]);
        acc[2]  = fmaf(h2lo(va.y), wu, acc[2]);
        acc[3]  = fmaf(h2hi(va.y), wu, acc[3]);
        acc[4]  = fmaf(h2lo(va.z), wu, acc[4]);
        acc[5]  = fmaf(h2hi(va.z), wu, acc[5]);
        acc[6]  = fmaf(h2lo(va.w), wu, acc[6]);
        acc[7]  = fmaf(h2hi(va.w), wu, acc[7]);
        acc[8]  = fmaf(h2lo(vc.x), wu, acc[8]);
        acc[9]  = fmaf(h2hi(vc.x), wu, acc[9]);
        acc[10] = fmaf(h2lo(vc.y), wu, acc[10]);
        acc[11] = fmaf(h2hi(vc.y), wu, acc[11]);
        acc[12] = fmaf(h2lo(vc.z), wu, acc[12]);
      }
    }
#pragma unroll
    for (int off = 1; off < 16; off <<= 1) {
#pragma unroll
      for (int d = 0; d < DHH; ++d) acc[d] += __shfl_xor(acc[d], off);
    }

    if (rok && li == 0) {
#pragma unroll
      for (int d = 0; d < DHH; ++d)
        att[((size_t)b * NN + i) * DIMX + h * DHH + d] = acc[d];
    }

    __builtin_amdgcn_s_setprio(0);
  }
}

// ---------------- Output projection: (B*N,78) @ (78,78) + b ----------------
// block = 320 threads (5 waves), 32 rows/block, thread = 2 rows x 4 cols.
__global__ __launch_bounds__(320) void proj_kernel(
    const float* __restrict__ att, const float* __restrict__ Wout,
    const float* __restrict__ bout, float* __restrict__ out) {
  __shared__ float Ws[DIMX][80];   // padded cols
  __shared__ float as[32][82];     // stride 82: conflict-free row reads
  __shared__ float bs[80];
  int tid = threadIdx.x;
  for (int e = tid; e < DIMX * 80; e += 320) {
    int r = e / 80, c = e % 80;
    Ws[r][c] = (c < DIMX) ? Wout[r * DIMX + c] : 0.f;
  }
  if (tid < 80) bs[tid] = (tid < DIMX) ? bout[tid] : 0.f;
  size_t row0 = (size_t)blockIdx.x * 32;
  for (int e = tid; e < 32 * DIMX; e += 320)
    as[e / DIMX][e % DIMX] = att[row0 * DIMX + e];
  __syncthreads();

  int r2 = tid / 20;   // 0..15 -> rows r2*2, r2*2+1
  int cq = tid % 20;   // 0..19 -> cols cq*4..cq*4+3 (last quad: 2 pad)
  int c0 = cq * 4;
  float acc0[4], acc1[4];
#pragma unroll
  for (int kk = 0; kk < 4; ++kk) { acc0[kk] = bs[c0 + kk]; acc1[kk] = bs[c0 + kk]; }

#pragma unroll 6
  for (int d = 0; d < DIMX; ++d) {
    float4 w = *(const float4*)&Ws[d][c0];
    float a0 = as[r2 * 2 + 0][d];
    float a1 = as[r2 * 2 + 1][d];
    acc0[0] = fmaf(a0, w.x, acc0[0]); acc0[1] = fmaf(a0, w.y, acc0[1]);
    acc0[2] = fmaf(a0, w.z, acc0[2]); acc0[3] = fmaf(a0, w.w, acc0[3]);
    acc1[0] = fmaf(a1, w.x, acc1[0]); acc1[1] = fmaf(a1, w.y, acc1[1]);
    acc1[2] = fmaf(a1, w.z, acc1[2]); acc1[3] = fmaf(a1, w.w, acc1[3]);
  }

  size_t r0o = (row0 + r2 * 2) * (size_t)DIMX;
  *(float2*)&out[r0o + c0]        = make_float2(acc0[0], acc0[1]);
  *(float2*)&out[r0o + DIMX + c0] = make_float2(acc1[0], acc1[1]);
  if (cq < 19) {
    *(float2*)&out[r0o + c0 + 2]        = make_float2(acc0[2], acc0[3]);
    *(float2*)&out[r0o + DIMX + c0 + 2] = make_float2(acc1[2], acc1[3]);
  }
}

extern "C" void kernel_launch(void* const* d_in, const int* in_sizes, int n_in,
                              void* d_out, int out_size, void* d_ws, size_t ws_size,
                              hipStream_t stream) {
  const float* x    = (const float*)d_in[0];
  const int*   mask = (const int*)d_in[1];
  const float* adj  = (const float*)d_in[2];
  const float* Wqkv = (const float*)d_in[3];
  const float* Wout = (const float*)d_in[4];
  const float* bout = (const float*)d_in[5];
  float* out = (float*)d_out;

  const size_t heads_rows = (size_t)BB * NH * NN;           // 49152
  float*   att = (float*)d_ws;                              // BB*NN*DIMX f32
  ushortx* qhp = (ushortx*)(att + (size_t)BB * NN * DIMX);  // heads_rows*QS ush
  ushortx* khp = qhp + heads_rows * QS;
  ushortx* vhp = khp + heads_rows * KS;

  const int NQ = 59;
  int qkv_threads = (BB * NN / 4) * NQ;
  qkv_kernel<<<(qkv_threads + 255) / 256, 256, 0, stream>>>(x, Wqkv, qhp, khp, vhp);
  attn_kernel<<<BB * NH * (NN / 64), 256, 0, stream>>>(qhp, khp, vhp, mask, adj, att);
  proj_kernel<<<BB * NN / 32, 320, 0, stream>>>(att, Wout, bout, out);
}